// Round 1
// baseline (463.058 us; speedup 1.0000x reference)
//
#include <hip/hip_runtime.h>
#include <hip/hip_fp16.h>

#define Bb 64
#define Nn 1024
#define Cc 558
#define CP1 559
#define CPAD 560
#define ITERS 20
#define PBLK 8
#define RPB (Nn/PBLK)      /* 128 rows per block */
#define WAVES 8
#define RPW (RPB/WAVES)    /* 16 rows per wave */
#define BLOCK 512

struct __align__(16) H8 { __half2 a, b, c, d; };

__device__ __forceinline__ float wave_sum(float v) {
#pragma unroll
    for (int off = 32; off > 0; off >>= 1) v += __shfl_xor(v, off, 64);
    return v;
}

// ---- detect visible_mask storage: 0 = int32, 1 = bytes(bool), 2 = float32 ----
__global__ void k_detect(const unsigned int* __restrict__ mw, int* __restrict__ flag) {
    __shared__ int fF, fB;
    if (threadIdx.x == 0) { fF = 0; fB = 0; }
    __syncthreads();
    for (int i = threadIdx.x; i < (Bb * Nn) / 4; i += blockDim.x) {
        unsigned w = mw[i];
        if (w == 0x3F800000u) fF = 1;
        else if (w > 1u) fB = 1;
    }
    __syncthreads();
    if (threadIdx.x == 0) *flag = fF ? 2 : (fB ? 1 : 0);
}

// ---- K0: per-row softmax. p0 = softmax(logits) as fp16 [row][CPAD], lse = log-sum-exp ----
__global__ __launch_bounds__(256) void k0_softmax(const float* __restrict__ logits,
        __half* __restrict__ p0, float* __restrict__ lse) {
    const int wave = threadIdx.x >> 6, lane = threadIdx.x & 63;
    const int r = (blockIdx.x << 2) + wave;
    const float* row = logits + (size_t)r * Cc;
    float e[8], e8 = 0.f, s = 0.f;
#pragma unroll
    for (int k = 0; k < 8; ++k) { e[k] = __expf(row[(k << 6) + lane]); s += e[k]; }
    if (lane < 46) { e8 = __expf(row[512 + lane]); s += e8; }
    s = wave_sum(s);
    const float inv = 1.f / s;
    __half* pr = p0 + (size_t)r * CPAD;
#pragma unroll
    for (int k = 0; k < 8; ++k) pr[(k << 6) + lane] = __float2half(e[k] * inv);
    if (lane < 46) pr[512 + lane] = __float2half(e8 * inv);
    if (lane == 0) lse[r] = __logf(s);
}

// ---- K1: per-batch mask processing + class loss ----
__global__ __launch_bounds__(256) void k1_batch(const float* __restrict__ logits,
        const int* __restrict__ labels, const void* __restrict__ maskp,
        const float* __restrict__ lse, const float* __restrict__ dustbin,
        float* __restrict__ class_part, float* __restrict__ inv_nvis,
        unsigned char* __restrict__ visc, float* __restrict__ dustp,
        const int* __restrict__ flag) {
    const int b = blockIdx.x, tid = threadIdx.x;
    const int mode = *flag;
    __shared__ int cs[256];
    __shared__ float red[256];
    int v[4]; int local = 0;
#pragma unroll
    for (int j = 0; j < 4; ++j) {
        const int n = tid * 4 + j;
        const int idx = b * Nn + n;
        int m;
        if (mode == 1)      m = ((const unsigned char*)maskp)[idx] != 0;
        else if (mode == 2) m = ((const float*)maskp)[idx] != 0.f;
        else                m = ((const int*)maskp)[idx] != 0;
        v[j] = m; local += m;
    }
    cs[tid] = local;
    __syncthreads();
    for (int off = 1; off < 256; off <<= 1) {   // inclusive scan (Hillis-Steele)
        int x = 0;
        if (tid >= off) x = cs[tid - off];
        __syncthreads();
        cs[tid] += x;
        __syncthreads();
    }
    const int nvis = cs[255];
    int run = cs[tid] - local;                   // exclusive prefix
    float nllsum = 0.f;
#pragma unroll
    for (int j = 0; j < 4; ++j) {
        const int n = tid * 4 + j;
        run += v[j];
        visc[b * Nn + n] = (unsigned char)v[j];
        if (v[j]) {
            const int rank = run - 1;            // >= 0 since v[j]=1 => run>=1
            const int tgt = labels[b * Nn + rank];
            nllsum += lse[b * Nn + n] - logits[((size_t)(b * Nn + n)) * Cc + tgt];
        }
    }
    red[tid] = nllsum;
    __syncthreads();
    for (int off = 128; off > 0; off >>= 1) {
        if (tid < off) red[tid] += red[tid + off];
        __syncthreads();
    }
    if (tid == 0) {
        class_part[b] = red[0] / (float)nvis;
        inv_nvis[b] = 1.f / (float)nvis;
        if (b == 0) *dustp = __expf(dustbin[0]);
    }
}

// ---- K2: one fused Sinkhorn iteration (row update + column partial sums) ----
__global__ __launch_bounds__(BLOCK) void k2_iter(const __half* __restrict__ p0,
        const unsigned char* __restrict__ visc, const float* __restrict__ inv_nvis,
        const float* __restrict__ dustp_p, float* __restrict__ eu_arr,
        const float* __restrict__ Rp, float* __restrict__ Wp, const int first) {
    __shared__ float evl[CP1];
    __shared__ float partl[WAVES][CPAD];
    const int b = blockIdx.x >> 3, p = blockIdx.x & 7, tid = threadIdx.x;
    for (int c = tid; c < CP1; c += BLOCK) {
        float ev = 1.f;                          // iteration 1: v = 0 => ev = 1
        if (!first) {
            float s = 0.f;
#pragma unroll
            for (int q = 0; q < PBLK; ++q) s += Rp[(size_t)((b * PBLK + q) * CPAD) + c];
            ev = 1.f / (559.f * s);
        }
        evl[c] = ev;
    }
    __syncthreads();
    const int wave = tid >> 6, lane = tid & 63;
    float evr[8];
#pragma unroll
    for (int k = 0; k < 8; ++k) evr[k] = evl[(lane << 3) + k];
    const float evt = (lane < 46) ? evl[512 + lane] : 0.f;
    const float evd = evl[558];
    const float dustp = *dustp_p;
    const float invn = inv_nvis[b];
    float pc[8] = {0.f, 0.f, 0.f, 0.f, 0.f, 0.f, 0.f, 0.f};
    float pct = 0.f, pcd = 0.f;
    const int row0 = b * Nn + p * RPB + wave * RPW;
    for (int i = 0; i < RPW; ++i) {
        const int r = row0 + i;
        if (!visc[r]) { if (lane == 0) eu_arr[r] = 0.f; continue; }
        const __half* pr = p0 + (size_t)r * CPAD;
        const H8 hv = *(const H8*)(pr + (lane << 3));
        const float x0 = __low2float(hv.a), x1 = __high2float(hv.a);
        const float x2 = __low2float(hv.b), x3 = __high2float(hv.b);
        const float x4 = __low2float(hv.c), x5 = __high2float(hv.c);
        const float x6 = __low2float(hv.d), x7 = __high2float(hv.d);
        const float xt = (lane < 46) ? __half2float(pr[512 + lane]) : 0.f;
        float s = x0*evr[0] + x1*evr[1] + x2*evr[2] + x3*evr[3]
                + x4*evr[4] + x5*evr[5] + x6*evr[6] + x7*evr[7] + xt*evt;
        s = wave_sum(s);
        s += dustp * evd;
        const float euv = invn / s;              // exp(u) = 1/(nvis * rowsum)
        if (lane == 0) eu_arr[r] = euv;
        pc[0] += x0*euv; pc[1] += x1*euv; pc[2] += x2*euv; pc[3] += x3*euv;
        pc[4] += x4*euv; pc[5] += x5*euv; pc[6] += x6*euv; pc[7] += x7*euv;
        pct += xt * euv; pcd += euv;
    }
#pragma unroll
    for (int k = 0; k < 8; ++k) partl[wave][(lane << 3) + k] = pc[k];
    if (lane < 46) partl[wave][512 + lane] = pct;
    if (lane == 0) partl[wave][558] = pcd * dustp;
    __syncthreads();
    for (int c = tid; c < CP1; c += BLOCK) {
        float s = 0.f;
#pragma unroll
        for (int w = 0; w < WAVES; ++w) s += partl[w][c];
        Wp[(size_t)((b * PBLK + p) * CPAD) + c] = s;
    }
}

// ---- K3: entropy of final plan (excluding dustbin column) ----
__global__ __launch_bounds__(BLOCK) void k3_final(const __half* __restrict__ p0,
        const float* __restrict__ eu_arr, const float* __restrict__ Rp,
        const float* __restrict__ inv_nvis, float* __restrict__ assign_part) {
    __shared__ float evl[CP1];
    __shared__ float red[WAVES];
    const int b = blockIdx.x >> 3, p = blockIdx.x & 7, tid = threadIdx.x;
    for (int c = tid; c < CP1; c += BLOCK) {
        float s = 0.f;
#pragma unroll
        for (int q = 0; q < PBLK; ++q) s += Rp[(size_t)((b * PBLK + q) * CPAD) + c];
        evl[c] = 1.f / (559.f * s);
    }
    __syncthreads();
    const int wave = tid >> 6, lane = tid & 63;
    float evr[8];
#pragma unroll
    for (int k = 0; k < 8; ++k) evr[k] = evl[(lane << 3) + k];
    const float evt = (lane < 46) ? evl[512 + lane] : 0.f;
    float acc = 0.f;
    const int row0 = b * Nn + p * RPB + wave * RPW;
    for (int i = 0; i < RPW; ++i) {
        const int r = row0 + i;
        const float euv = eu_arr[r];
        if (euv == 0.f) continue;                // invisible row: ent contributes 0
        const __half* pr = p0 + (size_t)r * CPAD;
        const H8 hv = *(const H8*)(pr + (lane << 3));
        const float x0 = __low2float(hv.a), x1 = __high2float(hv.a);
        const float x2 = __low2float(hv.b), x3 = __high2float(hv.b);
        const float x4 = __low2float(hv.c), x5 = __high2float(hv.c);
        const float x6 = __low2float(hv.d), x7 = __high2float(hv.d);
        const float xt = (lane < 46) ? __half2float(pr[512 + lane]) : 0.f;
        float P;
        P = x0*euv*evr[0]; acc -= P * __logf(P + 1e-8f);
        P = x1*euv*evr[1]; acc -= P * __logf(P + 1e-8f);
        P = x2*euv*evr[2]; acc -= P * __logf(P + 1e-8f);
        P = x3*euv*evr[3]; acc -= P * __logf(P + 1e-8f);
        P = x4*euv*evr[4]; acc -= P * __logf(P + 1e-8f);
        P = x5*euv*evr[5]; acc -= P * __logf(P + 1e-8f);
        P = x6*euv*evr[6]; acc -= P * __logf(P + 1e-8f);
        P = x7*euv*evr[7]; acc -= P * __logf(P + 1e-8f);
        P = xt*euv*evt;    acc -= P * __logf(P + 1e-8f);
    }
    acc = wave_sum(acc);
    if (lane == 0) red[wave] = acc;
    __syncthreads();
    if (tid == 0) {
        float s = 0.f;
#pragma unroll
        for (int w = 0; w < WAVES; ++w) s += red[w];
        assign_part[blockIdx.x] = s * inv_nvis[b];
    }
}

// ---- K4: combine ----
__global__ void k4_out(const float* __restrict__ class_part,
                       const float* __restrict__ assign_part, float* __restrict__ out) {
    const int b = threadIdx.x;   // 64 threads = 1 wave
    float v = class_part[b];
    float a = 0.f;
#pragma unroll
    for (int p = 0; p < PBLK; ++p) a += assign_part[b * PBLK + p];
    v += 0.5f * a;
    v = wave_sum(v);
    if (b == 0) out[0] = v * (1.f / 64.f);
}

extern "C" void kernel_launch(void* const* d_in, const int* in_sizes, int n_in,
                              void* d_out, int out_size, void* d_ws, size_t ws_size,
                              hipStream_t stream) {
    const float* logits = (const float*)d_in[0];
    const float* dustbin = (const float*)d_in[1];
    const int* labels = (const int*)d_in[2];
    const void* mask = d_in[3];
    float* out = (float*)d_out;

    char* ws = (char*)d_ws;
    size_t off = 0;
    __half* p0 = (__half*)(ws + off);          off += (size_t)Bb * Nn * CPAD * 2;  // 73.4 MB
    float* lse = (float*)(ws + off);           off += (size_t)Bb * Nn * 4;
    float* eu = (float*)(ws + off);            off += (size_t)Bb * Nn * 4;
    unsigned char* visc = (unsigned char*)(ws + off); off += (size_t)Bb * Nn;
    float* inv_nvis = (float*)(ws + off);      off += Bb * 4;
    float* parts = (float*)(ws + off);         off += 2ull * Bb * PBLK * CPAD * 4;
    float* class_part = (float*)(ws + off);    off += Bb * 4;
    float* assign_part = (float*)(ws + off);   off += Bb * PBLK * 4;
    float* dustp = (float*)(ws + off);         off += 16;
    int* flag = (int*)(ws + off);              off += 16;
    const size_t SLOT = (size_t)Bb * PBLK * CPAD;  // floats per parts buffer

    k_detect<<<1, 256, 0, stream>>>((const unsigned int*)mask, flag);
    k0_softmax<<<(Bb * Nn) / 4, 256, 0, stream>>>(logits, p0, lse);
    k1_batch<<<Bb, 256, 0, stream>>>(logits, labels, mask, lse, dustbin,
                                     class_part, inv_nvis, visc, dustp, flag);
    for (int t = 0; t < ITERS; ++t) {
        float* Wb = parts + (size_t)(t & 1) * SLOT;
        const float* Rb = parts + (size_t)((t + 1) & 1) * SLOT;
        k2_iter<<<Bb * PBLK, BLOCK, 0, stream>>>(p0, visc, inv_nvis, dustp, eu, Rb, Wb,
                                                 (t == 0) ? 1 : 0);
    }
    k3_final<<<Bb * PBLK, BLOCK, 0, stream>>>(p0, eu,
            parts + (size_t)((ITERS - 1) & 1) * SLOT, inv_nvis, assign_part);
    k4_out<<<1, 64, 0, stream>>>(class_part, assign_part, out);
    (void)in_sizes; (void)n_in; (void)out_size; (void)ws_size;
}